// Round 4
// baseline (311.803 us; speedup 1.0000x reference)
//
#include <hip/hip_runtime.h>
#include <stdint.h>

// ---------------------------------------------------------------------------
// CausalSelfAttention: x[4,2048,1024] -> qkv -> flash attn -> proj
// Round 7 (= round 6 resubmitted after infra failure, no code change):
// k_flash double-buffered K/V staging with counted vmcnt(4) (T3/T4 pattern):
// issue next KV tile's global_load_lds BEFORE the wait, so fetch latency
// hides under the current tile's QK^T/softmax/PV.  Previously each tile did
// issue -> __syncthreads() (vmcnt(0) drain) -> compute, exposing full
// L2/HBM latency per tile (MfmaUtil 17%, occ 31%).
// GEMM (256x256 4-phase derived-waits) unchanged from round 5.
// ---------------------------------------------------------------------------

typedef __attribute__((ext_vector_type(8))) short short8;   // 8 bf16 (4 VGPRs)
typedef __attribute__((ext_vector_type(4))) float floatx4;  // MFMA C/D frag

#define AS1C(p) ((const __attribute__((address_space(1))) void*)(p))
#define AS3(p)  ((__attribute__((address_space(3))) void*)(p))
#define GL16(src, dst) __builtin_amdgcn_global_load_lds(AS1C(src), AS3(dst), 16, 0, 0)
#define BARRIER() do { asm volatile("" ::: "memory"); __builtin_amdgcn_s_barrier(); asm volatile("" ::: "memory"); } while (0)

__device__ __forceinline__ unsigned short f2bf(float f) {
  unsigned int u = __builtin_bit_cast(unsigned int, f);
  u = (u + 0x7fffu + ((u >> 16) & 1u)) >> 16;   // RNE
  return (unsigned short)u;
}
__device__ __forceinline__ unsigned short f2bf_trunc(float f) {
  return (unsigned short)(__builtin_bit_cast(unsigned int, f) >> 16);
}

// ---- fp32 -> bf16 elementwise (x4 vectorized) ----
__global__ void k_cvt(const float* __restrict__ in, unsigned short* __restrict__ out, int n4) {
  int i = blockIdx.x * blockDim.x + threadIdx.x;
  if (i < n4) {
    float4 v = ((const float4*)in)[i];
    ushort4 o;
    o.x = f2bf(v.x); o.y = f2bf(v.y); o.z = f2bf(v.z); o.w = f2bf(v.w);
    ((ushort4*)out)[i] = o;
  }
}

// ---- transpose fp32 [K][N] -> bf16 [N][K] (weights) ----
__global__ void k_tw(const float* __restrict__ in, unsigned short* __restrict__ out, int K, int N) {
  __shared__ float t[32][33];
  int n0 = blockIdx.x * 32, k0 = blockIdx.y * 32;
  int tx = threadIdx.x, ty = threadIdx.y;
#pragma unroll
  for (int i = 0; i < 4; i++)
    t[ty + 8 * i][tx] = in[(size_t)(k0 + ty + 8 * i) * N + n0 + tx];
  __syncthreads();
#pragma unroll
  for (int i = 0; i < 4; i++)
    out[(size_t)(n0 + ty + 8 * i) * K + k0 + tx] = f2bf(t[tx][ty + 8 * i]);
}

// ---- transpose V slice of qkv (bf16) -> VT[bh][d][t] ----
__global__ void k_tv(const unsigned short* __restrict__ qkv, unsigned short* __restrict__ vt) {
  __shared__ unsigned short t[32][33];
  int t0 = blockIdx.x * 32;         // time tile
  int d0 = blockIdx.y * 32;         // head-dim tile (0 or 32)
  int bh = blockIdx.z;              // 0..63
  int b = bh >> 4, h = bh & 15;
  int tx = threadIdx.x, ty = threadIdx.y;
#pragma unroll
  for (int i = 0; i < 4; i++)
    t[ty + 8 * i][tx] = qkv[(size_t)(b * 2048 + t0 + ty + 8 * i) * 3072 + 2048 + h * 64 + d0 + tx];
  __syncthreads();
#pragma unroll
  for (int i = 0; i < 4; i++)
    vt[(size_t)(bh * 64 + d0 + ty + 8 * i) * 2048 + t0 + tx] = t[tx][ty + 8 * i];
}

// ---------------------------------------------------------------------------
// 256x256-tile bf16 GEMM, C = A[M,K] @ Bt[N,K]^T + bias.  4-phase schedule,
// derived waits (tile t stages tile t+2 into its own parity buffer; one
// counted vmcnt(8) per K-tile).  Unchanged from round 5.
// ---------------------------------------------------------------------------
template <int OUT_F32>
__global__ __launch_bounds__(512, 2)
void k_gemm8(const unsigned short* __restrict__ A,
             const unsigned short* __restrict__ Bt,
             const float* __restrict__ bias,
             void* __restrict__ Cout, int M, int N, int K) {
  __shared__ unsigned short lA[2][256 * 64];   // 64 KiB
  __shared__ unsigned short lB[2][256 * 64];   // 64 KiB
  int tid = threadIdx.x;
  int lane = tid & 63, wv = tid >> 6;          // 8 waves
  int lc = lane & 15, quad = lane >> 4;
  int sw = lc & 7;

  // T1: XCD-aware block swizzle (both launches have nwg % 8 == 0)
  unsigned nbx = gridDim.x;
  unsigned nwg = nbx * gridDim.y;
  unsigned flat = blockIdx.y * nbx + blockIdx.x;
  unsigned cpx = nwg >> 3;
  unsigned tile = (flat & 7u) * cpx + (flat >> 3);
  int n0 = (int)(tile % nbx) * 256;
  int m0 = (int)(tile / nbx) * 256;

  int wm = (wv >> 2) * 128;   // 0,128
  int wn = (wv & 3) * 64;     // 0,64,128,192

  floatx4 acc[8][4];
#pragma unroll
  for (int i = 0; i < 8; i++)
#pragma unroll
    for (int j = 0; j < 4; j++) acc[i][j] = (floatx4){0.f, 0.f, 0.f, 0.f};

  // staging geometry: one gload issue = 512 thr x 16B = 8 KiB = 64 rows
  int srow = tid >> 3;                          // 0..63
  int scol = ((tid & 7) ^ (srow & 7)) * 8;      // inverse-swizzled source chunk
  const unsigned short* gA = A + (size_t)(m0 + srow) * K + scol;
  const unsigned short* gB = Bt + (size_t)(n0 + srow) * K + scol;

  int NT = K >> 6;

  // prologue: stage K-tiles 0 (buf0) and 1 (buf1); wait tile 0 landed.
#pragma unroll
  for (int i = 0; i < 4; i++) GL16(gA + (size_t)(i * 64) * K, &lA[0][i * 4096 + wv * 512]);
#pragma unroll
  for (int i = 0; i < 4; i++) GL16(gB + (size_t)(i * 64) * K, &lB[0][i * 4096 + wv * 512]);
#pragma unroll
  for (int i = 0; i < 4; i++) GL16(gA + (size_t)(i * 64) * K + 64, &lA[1][i * 4096 + wv * 512]);
#pragma unroll
  for (int i = 0; i < 4; i++) GL16(gB + (size_t)(i * 64) * K + 64, &lB[1][i * 4096 + wv * 512]);
  asm volatile("s_waitcnt vmcnt(8)" ::: "memory");
  __builtin_amdgcn_s_barrier();
  asm volatile("" ::: "memory");

  for (int t = 0; t < NT; ++t) {
    const unsigned short* bufA = lA[t & 1];
    const unsigned short* bufB = lB[t & 1];
    unsigned short* stA = lA[t & 1];            // tile t+2 lands in same parity
    unsigned short* stB = lB[t & 1];
    int k2 = (t + 2) << 6;
    bool st = (t + 2) < NT;

    short8 af[4][2], bf[4][2];

    // ---- P1: read af m0-3 (8) + bf n0-1 (4); Q1 ----
#pragma unroll
    for (int m = 0; m < 4; m++)
#pragma unroll
      for (int ks = 0; ks < 2; ks++)
        af[m][ks] = *(const short8*)(bufA + (wm + m * 16 + lc) * 64 + (((ks * 4 + quad) ^ sw) * 8));
#pragma unroll
    for (int n = 0; n < 2; n++)
#pragma unroll
      for (int ks = 0; ks < 2; ks++)
        bf[n][ks] = *(const short8*)(bufB + (wn + n * 16 + lc) * 64 + (((ks * 4 + quad) ^ sw) * 8));
    BARRIER();
    __builtin_amdgcn_s_setprio(1);
#pragma unroll
    for (int m = 0; m < 4; m++)
#pragma unroll
      for (int n = 0; n < 2; n++)
#pragma unroll
        for (int ks = 0; ks < 2; ks++)
          acc[m][n] = __builtin_amdgcn_mfma_f32_16x16x32_bf16(af[m][ks], bf[n][ks], acc[m][n], 0, 0, 0);
    __builtin_amdgcn_s_setprio(0);
    BARRIER();

    // ---- P2: read bf n2-3 (4); Q2 ----  (B of this buffer dead after this)
#pragma unroll
    for (int n = 2; n < 4; n++)
#pragma unroll
      for (int ks = 0; ks < 2; ks++)
        bf[n][ks] = *(const short8*)(bufB + (wn + n * 16 + lc) * 64 + (((ks * 4 + quad) ^ sw) * 8));
    BARRIER();
    __builtin_amdgcn_s_setprio(1);
#pragma unroll
    for (int m = 0; m < 4; m++)
#pragma unroll
      for (int n = 0; n < 2; n++)
#pragma unroll
        for (int ks = 0; ks < 2; ks++)
          acc[m][n + 2] = __builtin_amdgcn_mfma_f32_16x16x32_bf16(af[m][ks], bf[n + 2][ks], acc[m][n + 2], 0, 0, 0);
    __builtin_amdgcn_s_setprio(0);
    BARRIER();

    // ---- P3: read af m4-7 (8, reusing regs); stage tile t+2 B; Q3 ----
#pragma unroll
    for (int m = 0; m < 4; m++)
#pragma unroll
      for (int ks = 0; ks < 2; ks++)
        af[m][ks] = *(const short8*)(bufA + (wm + (m + 4) * 16 + lc) * 64 + (((ks * 4 + quad) ^ sw) * 8));
    if (st) {
#pragma unroll
      for (int i = 0; i < 4; i++)
        GL16(gB + (size_t)(i * 64) * K + k2, stB + i * 4096 + wv * 512);
    }
    BARRIER();
    __builtin_amdgcn_s_setprio(1);
#pragma unroll
    for (int m = 0; m < 4; m++)
#pragma unroll
      for (int n = 0; n < 2; n++)
#pragma unroll
        for (int ks = 0; ks < 2; ks++)
          acc[m + 4][n] = __builtin_amdgcn_mfma_f32_16x16x32_bf16(af[m][ks], bf[n][ks], acc[m + 4][n], 0, 0, 0);
    __builtin_amdgcn_s_setprio(0);
    BARRIER();   // A of this buffer dead after this

    // ---- P4: stage tile t+2 A; Q4 (regs only); counted vmcnt; barrier ----
    if (st) {
#pragma unroll
      for (int i = 0; i < 4; i++)
        GL16(gA + (size_t)(i * 64) * K + k2, stA + i * 4096 + wv * 512);
    }
    __builtin_amdgcn_s_setprio(1);
#pragma unroll
    for (int m = 0; m < 4; m++)
#pragma unroll
      for (int n = 0; n < 2; n++)
#pragma unroll
        for (int ks = 0; ks < 2; ks++)
          acc[m + 4][n + 2] = __builtin_amdgcn_mfma_f32_16x16x32_bf16(af[m][ks], bf[n + 2][ks], acc[m + 4][n + 2], 0, 0, 0);
    __builtin_amdgcn_s_setprio(0);
    // tile t+1 fully landed iff only tile t+2's 8 loads remain in flight.
    if (st) asm volatile("s_waitcnt vmcnt(8)" ::: "memory");
    else    asm volatile("s_waitcnt vmcnt(0)" ::: "memory");
    BARRIER();
  }

  // ---- epilogue ----
  float bv[4];
#pragma unroll
  for (int j = 0; j < 4; j++) bv[j] = bias[n0 + wn + j * 16 + lc];
#pragma unroll
  for (int i = 0; i < 8; i++) {
#pragma unroll
    for (int j = 0; j < 4; j++) {
#pragma unroll
      for (int r = 0; r < 4; r++) {
        size_t idx = (size_t)(m0 + wm + i * 16 + quad * 4 + r) * N + (n0 + wn + j * 16 + lc);
        float v = acc[i][j][r] + bv[j];
        if (OUT_F32) ((float*)Cout)[idx] = v;
        else         ((unsigned short*)Cout)[idx] = f2bf(v);
      }
    }
  }
}

// ---- flash attention, paired q-tiles (j, 31-j), double-buffered K/V ----
#define LP_STRIDE 68   // pad: pf b128 reads land 2-way/bank (free)
__global__ __launch_bounds__(256, 4)
void k_flash(const unsigned short* __restrict__ qkv,
             const unsigned short* __restrict__ vt,
             unsigned short* __restrict__ y) {
  __shared__ unsigned short lK[2][64 * 64];    // 16 KiB
  __shared__ unsigned short lVT[2][64 * 64];   // 16 KiB
  __shared__ unsigned short lP[4][2][16 * LP_STRIDE];  // 17.4 KiB
  int tid = threadIdx.x, lane = tid & 63, wv = tid >> 6;
  int lc = lane & 15, quad = lane >> 4;
  int sw = lc & 7;
  int j  = blockIdx.x;          // 0..15 pair index
  int bh = blockIdx.y;          // 0..63
  int b = bh >> 4, h = bh & 15;
  int qtA = j, qtB = 31 - j;
  int qrA = qtA * 64 + wv * 16;
  int qrB = qtB * 64 + wv * 16;

  short8 qfA[2], qfB[2];
  {
    const unsigned short* qp = qkv + (size_t)(b * 2048 + qrA + lc) * 3072 + h * 64 + quad * 8;
    qfA[0] = *(const short8*)qp;
    qfA[1] = *(const short8*)(qp + 32);
  }
  {
    const unsigned short* qp = qkv + (size_t)(b * 2048 + qrB + lc) * 3072 + h * 64 + quad * 8;
    qfB[0] = *(const short8*)qp;
    qfB[1] = *(const short8*)(qp + 32);
  }

  float rsA[4] = {0.f, 0.f, 0.f, 0.f}, rsB[4] = {0.f, 0.f, 0.f, 0.f};
  floatx4 oA[4], oB[4];
#pragma unroll
  for (int dt = 0; dt < 4; dt++) {
    oA[dt] = (floatx4){0.f, 0.f, 0.f, 0.f};
    oB[dt] = (floatx4){0.f, 0.f, 0.f, 0.f};
  }

  int srow = tid >> 3;
  int scol = ((tid & 7) ^ (srow & 7)) * 8;    // swizzled gather column
  const unsigned short* gK = qkv + (size_t)(b * 2048 + srow) * 3072 + 1024 + h * 64 + scol;
  const unsigned short* gV = vt + (size_t)(bh * 64 + srow) * 2048 + scol;

  const float SC2 = 0.18033688011f;   // (1/sqrt(64)) * log2(e)
  int nt = qtB + 1;                   // >= 17

  // prologue: stage KV tile 0 into buffer 0 (4 loads/wave)
#pragma unroll
  for (int c = 0; c < 2; c++) {
    GL16(gK + (size_t)(32 * c) * 3072, &lK[0][(32 * c + 8 * wv) * 64]);
    GL16(gV + (size_t)(32 * c) * 2048, &lVT[0][(32 * c + 8 * wv) * 64]);
  }

  for (int kv = 0; kv < nt; kv++) {
    int cur = kv & 1;
    // issue next tile's loads BEFORE waiting; then counted vmcnt(4):
    // the 4 newest (tile kv+1) stay in flight, tile kv proven landed.
    if (kv + 1 < nt) {
      int kn0 = (kv + 1) * 64;
#pragma unroll
      for (int c = 0; c < 2; c++) {
        GL16(gK + (size_t)(kn0 + 32 * c) * 3072, &lK[cur ^ 1][(32 * c + 8 * wv) * 64]);
        GL16(gV + (size_t)(32 * c) * 2048 + kn0, &lVT[cur ^ 1][(32 * c + 8 * wv) * 64]);
      }
      asm volatile("s_waitcnt vmcnt(4)" ::: "memory");
    } else {
      asm volatile("s_waitcnt vmcnt(0)" ::: "memory");
    }
    BARRIER();   // tile kv visible to all waves

    const unsigned short* cK = lK[cur];
    const unsigned short* cVT = lVT[cur];
    int kv0 = kv * 64;
    bool withA = (kv <= qtA);

    // ---- S = Q K^T for both q-tiles, sharing K fragments ----
    floatx4 sB[4], sA[4];
#pragma unroll
    for (int n = 0; n < 4; n++) {
      short8 kf0 = *(const short8*)(cK + (n * 16 + lc) * 64 + ((quad ^ sw) * 8));
      short8 kf1 = *(const short8*)(cK + (n * 16 + lc) * 64 + (((4 + quad) ^ sw) * 8));
      floatx4 t = (floatx4){0.f, 0.f, 0.f, 0.f};
      t = __builtin_amdgcn_mfma_f32_16x16x32_bf16(qfB[0], kf0, t, 0, 0, 0);
      t = __builtin_amdgcn_mfma_f32_16x16x32_bf16(qfB[1], kf1, t, 0, 0, 0);
      sB[n] = t;
      if (withA) {
        floatx4 u = (floatx4){0.f, 0.f, 0.f, 0.f};
        u = __builtin_amdgcn_mfma_f32_16x16x32_bf16(qfA[0], kf0, u, 0, 0, 0);
        u = __builtin_amdgcn_mfma_f32_16x16x32_bf16(qfA[1], kf1, u, 0, 0, 0);
        sA[n] = u;
      }
    }

    // ---- softmax numerators (no max subtraction), P -> LDS (trunc pack) ----
    {
      bool diag = (kv == qtB);
#pragma unroll
      for (int n = 0; n < 4; n++)
#pragma unroll
        for (int r = 0; r < 4; r++) {
          float arg = sB[n][r] * SC2;
          if (diag && (kv0 + n * 16 + lc > qrB + quad * 4 + r)) arg = -__builtin_inff();
          float p = __builtin_amdgcn_exp2f(arg);
          rsB[r] += p;
          lP[wv][0][(quad * 4 + r) * LP_STRIDE + n * 16 + lc] = f2bf_trunc(p);
        }
    }
    if (withA) {
      bool diag = (kv == qtA);
#pragma unroll
      for (int n = 0; n < 4; n++)
#pragma unroll
        for (int r = 0; r < 4; r++) {
          float arg = sA[n][r] * SC2;
          if (diag && (kv0 + n * 16 + lc > qrA + quad * 4 + r)) arg = -__builtin_inff();
          float p = __builtin_amdgcn_exp2f(arg);
          rsA[r] += p;
          lP[wv][1][(quad * 4 + r) * LP_STRIDE + n * 16 + lc] = f2bf_trunc(p);
        }
    }

    // ---- O += P @ V, sharing V fragments (same-wave lgkmcnt orders lP) ----
#pragma unroll
    for (int s2 = 0; s2 < 2; s2++) {
      short8 pfB = *(const short8*)(&lP[wv][0][0] + lc * LP_STRIDE + s2 * 32 + quad * 8);
      short8 pfA;
      if (withA) pfA = *(const short8*)(&lP[wv][1][0] + lc * LP_STRIDE + s2 * 32 + quad * 8);
#pragma unroll
      for (int dt = 0; dt < 4; dt++) {
        short8 vf = *(const short8*)(cVT + (dt * 16 + lc) * 64 + (((s2 * 4 + quad) ^ sw) * 8));
        oB[dt] = __builtin_amdgcn_mfma_f32_16x16x32_bf16(pfB, vf, oB[dt], 0, 0, 0);
        if (withA) oA[dt] = __builtin_amdgcn_mfma_f32_16x16x32_bf16(pfA, vf, oA[dt], 0, 0, 0);
      }
    }
    BARRIER();   // all waves done reading buf[cur] -> safe to overwrite next iter
  }

  // ---- epilogue: one row-sum butterfly, normalize, store both tiles ----
#pragma unroll
  for (int off = 1; off < 16; off <<= 1)
#pragma unroll
    for (int r = 0; r < 4; r++) {
      rsA[r] += __shfl_xor(rsA[r], off);
      rsB[r] += __shfl_xor(rsB[r], off);
    }
#pragma unroll
  for (int r = 0; r < 4; r++) {
    float invA = 1.0f / rsA[r];
    float invB = 1.0f / rsB[r];
#pragma unroll
    for (int dt = 0; dt < 4; dt++) {
      size_t ia = (size_t)(b * 2048 + qrA + quad * 4 + r) * 1024 + h * 64 + dt * 16 + lc;
      size_t ib = (size_t)(b * 2048 + qrB + quad * 4 + r) * 1024 + h * 64 + dt * 16 + lc;
      y[ia] = f2bf(oA[dt][r] * invA);
      y[ib] = f2bf(oB[dt][r] * invB);
    }
  }
}

extern "C" void kernel_launch(void* const* d_in, const int* in_sizes, int n_in,
                              void* d_out, int out_size, void* d_ws, size_t ws_size,
                              hipStream_t stream) {
  const float* x      = (const float*)d_in[0];
  const float* W_attn = (const float*)d_in[1];
  const float* b_attn = (const float*)d_in[2];
  const float* W_proj = (const float*)d_in[3];
  const float* b_proj = (const float*)d_in[4];

  char* ws = (char*)d_ws;
  unsigned short* xb     = (unsigned short*)ws;                    // 16.8 MB (reused as y)
  unsigned short* wattnT = (unsigned short*)(ws + 16777216);       // 6.3 MB
  unsigned short* wprojT = (unsigned short*)(ws + 23068672);       // 2.1 MB
  unsigned short* qkv    = (unsigned short*)(ws + 25165824);       // 50.3 MB
  unsigned short* vt     = (unsigned short*)(ws + 75497472);       // 16.8 MB -> total 92.3 MB
  unsigned short* y      = xb;   // xb dead after QKV GEMM

  k_cvt<<<8192, 256, 0, stream>>>(x, xb, 8388608 / 4);
  k_tw<<<dim3(96, 32), dim3(32, 8), 0, stream>>>(W_attn, wattnT, 1024, 3072);
  k_tw<<<dim3(32, 32), dim3(32, 8), 0, stream>>>(W_proj, wprojT, 1024, 1024);
  // QKV GEMM: grid 12x32 = 384 blocks (256x256 tiles)
  k_gemm8<0><<<dim3(12, 32), 512, 0, stream>>>(xb, wattnT, b_attn, qkv, 8192, 3072, 1024);
  k_tv<<<dim3(64, 2, 64), dim3(32, 8), 0, stream>>>(qkv, vt);
  k_flash<<<dim3(16, 64), 256, 0, stream>>>(qkv, vt, y);
  // proj GEMM: grid 4x32 = 128 blocks
  k_gemm8<1><<<dim3(4, 32), 512, 0, stream>>>(y, wprojT, b_proj, d_out, 8192, 1024, 1024);
}

// Round 5
// 265.361 us; speedup vs baseline: 1.1750x; 1.1750x over previous
//
#include <hip/hip_runtime.h>
#include <stdint.h>

// ---------------------------------------------------------------------------
// CausalSelfAttention: x[4,2048,1024] -> qkv -> flash attn -> proj
// Round 8: k_flash reverted to the round-3 structure (single-buffered K/V,
// 33.8 KB LDS -> 4 blocks/CU; the round-7 dbuf cost occupancy 4->3 and
// regressed).  NEW: XCD-grouped block remap so all 16 q-pair blocks sharing
// one (b,h)'s K/V land on the same XCD (FETCH_SIZE was 170 MB vs ~50 MB
// unique -> cross-XCD L2 duplication); + s_setprio around MFMA clusters
// (m191: helps attn's independent desynced blocks).
// GEMMs unchanged (256x256 4-phase derived-waits).
// ---------------------------------------------------------------------------

typedef __attribute__((ext_vector_type(8))) short short8;   // 8 bf16 (4 VGPRs)
typedef __attribute__((ext_vector_type(4))) float floatx4;  // MFMA C/D frag

#define AS1C(p) ((const __attribute__((address_space(1))) void*)(p))
#define AS3(p)  ((__attribute__((address_space(3))) void*)(p))
#define GL16(src, dst) __builtin_amdgcn_global_load_lds(AS1C(src), AS3(dst), 16, 0, 0)
#define BARRIER() do { asm volatile("" ::: "memory"); __builtin_amdgcn_s_barrier(); asm volatile("" ::: "memory"); } while (0)

__device__ __forceinline__ unsigned short f2bf(float f) {
  unsigned int u = __builtin_bit_cast(unsigned int, f);
  u = (u + 0x7fffu + ((u >> 16) & 1u)) >> 16;   // RNE
  return (unsigned short)u;
}
__device__ __forceinline__ unsigned short f2bf_trunc(float f) {
  return (unsigned short)(__builtin_bit_cast(unsigned int, f) >> 16);
}

// ---- fp32 -> bf16 elementwise (x4 vectorized) ----
__global__ void k_cvt(const float* __restrict__ in, unsigned short* __restrict__ out, int n4) {
  int i = blockIdx.x * blockDim.x + threadIdx.x;
  if (i < n4) {
    float4 v = ((const float4*)in)[i];
    ushort4 o;
    o.x = f2bf(v.x); o.y = f2bf(v.y); o.z = f2bf(v.z); o.w = f2bf(v.w);
    ((ushort4*)out)[i] = o;
  }
}

// ---- transpose fp32 [K][N] -> bf16 [N][K] (weights) ----
__global__ void k_tw(const float* __restrict__ in, unsigned short* __restrict__ out, int K, int N) {
  __shared__ float t[32][33];
  int n0 = blockIdx.x * 32, k0 = blockIdx.y * 32;
  int tx = threadIdx.x, ty = threadIdx.y;
#pragma unroll
  for (int i = 0; i < 4; i++)
    t[ty + 8 * i][tx] = in[(size_t)(k0 + ty + 8 * i) * N + n0 + tx];
  __syncthreads();
#pragma unroll
  for (int i = 0; i < 4; i++)
    out[(size_t)(n0 + ty + 8 * i) * K + k0 + tx] = f2bf(t[tx][ty + 8 * i]);
}

// ---- transpose V slice of qkv (bf16) -> VT[bh][d][t] ----
__global__ void k_tv(const unsigned short* __restrict__ qkv, unsigned short* __restrict__ vt) {
  __shared__ unsigned short t[32][33];
  int t0 = blockIdx.x * 32;         // time tile
  int d0 = blockIdx.y * 32;         // head-dim tile (0 or 32)
  int bh = blockIdx.z;              // 0..63
  int b = bh >> 4, h = bh & 15;
  int tx = threadIdx.x, ty = threadIdx.y;
#pragma unroll
  for (int i = 0; i < 4; i++)
    t[ty + 8 * i][tx] = qkv[(size_t)(b * 2048 + t0 + ty + 8 * i) * 3072 + 2048 + h * 64 + d0 + tx];
  __syncthreads();
#pragma unroll
  for (int i = 0; i < 4; i++)
    vt[(size_t)(bh * 64 + d0 + ty + 8 * i) * 2048 + t0 + tx] = t[tx][ty + 8 * i];
}

// ---------------------------------------------------------------------------
// 256x256-tile bf16 GEMM, C = A[M,K] @ Bt[N,K]^T + bias.  4-phase schedule,
// derived waits (tile t stages tile t+2 into its own parity buffer; one
// counted vmcnt(8) per K-tile).  Unchanged from round 5.
// ---------------------------------------------------------------------------
template <int OUT_F32>
__global__ __launch_bounds__(512, 2)
void k_gemm8(const unsigned short* __restrict__ A,
             const unsigned short* __restrict__ Bt,
             const float* __restrict__ bias,
             void* __restrict__ Cout, int M, int N, int K) {
  __shared__ unsigned short lA[2][256 * 64];   // 64 KiB
  __shared__ unsigned short lB[2][256 * 64];   // 64 KiB
  int tid = threadIdx.x;
  int lane = tid & 63, wv = tid >> 6;          // 8 waves
  int lc = lane & 15, quad = lane >> 4;
  int sw = lc & 7;

  // T1: XCD-aware block swizzle (both launches have nwg % 8 == 0)
  unsigned nbx = gridDim.x;
  unsigned nwg = nbx * gridDim.y;
  unsigned flat = blockIdx.y * nbx + blockIdx.x;
  unsigned cpx = nwg >> 3;
  unsigned tile = (flat & 7u) * cpx + (flat >> 3);
  int n0 = (int)(tile % nbx) * 256;
  int m0 = (int)(tile / nbx) * 256;

  int wm = (wv >> 2) * 128;   // 0,128
  int wn = (wv & 3) * 64;     // 0,64,128,192

  floatx4 acc[8][4];
#pragma unroll
  for (int i = 0; i < 8; i++)
#pragma unroll
    for (int j = 0; j < 4; j++) acc[i][j] = (floatx4){0.f, 0.f, 0.f, 0.f};

  // staging geometry: one gload issue = 512 thr x 16B = 8 KiB = 64 rows
  int srow = tid >> 3;                          // 0..63
  int scol = ((tid & 7) ^ (srow & 7)) * 8;      // inverse-swizzled source chunk
  const unsigned short* gA = A + (size_t)(m0 + srow) * K + scol;
  const unsigned short* gB = Bt + (size_t)(n0 + srow) * K + scol;

  int NT = K >> 6;

  // prologue: stage K-tiles 0 (buf0) and 1 (buf1); wait tile 0 landed.
#pragma unroll
  for (int i = 0; i < 4; i++) GL16(gA + (size_t)(i * 64) * K, &lA[0][i * 4096 + wv * 512]);
#pragma unroll
  for (int i = 0; i < 4; i++) GL16(gB + (size_t)(i * 64) * K, &lB[0][i * 4096 + wv * 512]);
#pragma unroll
  for (int i = 0; i < 4; i++) GL16(gA + (size_t)(i * 64) * K + 64, &lA[1][i * 4096 + wv * 512]);
#pragma unroll
  for (int i = 0; i < 4; i++) GL16(gB + (size_t)(i * 64) * K + 64, &lB[1][i * 4096 + wv * 512]);
  asm volatile("s_waitcnt vmcnt(8)" ::: "memory");
  __builtin_amdgcn_s_barrier();
  asm volatile("" ::: "memory");

  for (int t = 0; t < NT; ++t) {
    const unsigned short* bufA = lA[t & 1];
    const unsigned short* bufB = lB[t & 1];
    unsigned short* stA = lA[t & 1];            // tile t+2 lands in same parity
    unsigned short* stB = lB[t & 1];
    int k2 = (t + 2) << 6;
    bool st = (t + 2) < NT;

    short8 af[4][2], bf[4][2];

    // ---- P1: read af m0-3 (8) + bf n0-1 (4); Q1 ----
#pragma unroll
    for (int m = 0; m < 4; m++)
#pragma unroll
      for (int ks = 0; ks < 2; ks++)
        af[m][ks] = *(const short8*)(bufA + (wm + m * 16 + lc) * 64 + (((ks * 4 + quad) ^ sw) * 8));
#pragma unroll
    for (int n = 0; n < 2; n++)
#pragma unroll
      for (int ks = 0; ks < 2; ks++)
        bf[n][ks] = *(const short8*)(bufB + (wn + n * 16 + lc) * 64 + (((ks * 4 + quad) ^ sw) * 8));
    BARRIER();
    __builtin_amdgcn_s_setprio(1);
#pragma unroll
    for (int m = 0; m < 4; m++)
#pragma unroll
      for (int n = 0; n < 2; n++)
#pragma unroll
        for (int ks = 0; ks < 2; ks++)
          acc[m][n] = __builtin_amdgcn_mfma_f32_16x16x32_bf16(af[m][ks], bf[n][ks], acc[m][n], 0, 0, 0);
    __builtin_amdgcn_s_setprio(0);
    BARRIER();

    // ---- P2: read bf n2-3 (4); Q2 ----  (B of this buffer dead after this)
#pragma unroll
    for (int n = 2; n < 4; n++)
#pragma unroll
      for (int ks = 0; ks < 2; ks++)
        bf[n][ks] = *(const short8*)(bufB + (wn + n * 16 + lc) * 64 + (((ks * 4 + quad) ^ sw) * 8));
    BARRIER();
    __builtin_amdgcn_s_setprio(1);
#pragma unroll
    for (int m = 0; m < 4; m++)
#pragma unroll
      for (int n = 0; n < 2; n++)
#pragma unroll
        for (int ks = 0; ks < 2; ks++)
          acc[m][n + 2] = __builtin_amdgcn_mfma_f32_16x16x32_bf16(af[m][ks], bf[n + 2][ks], acc[m][n + 2], 0, 0, 0);
    __builtin_amdgcn_s_setprio(0);
    BARRIER();

    // ---- P3: read af m4-7 (8, reusing regs); stage tile t+2 B; Q3 ----
#pragma unroll
    for (int m = 0; m < 4; m++)
#pragma unroll
      for (int ks = 0; ks < 2; ks++)
        af[m][ks] = *(const short8*)(bufA + (wm + (m + 4) * 16 + lc) * 64 + (((ks * 4 + quad) ^ sw) * 8));
    if (st) {
#pragma unroll
      for (int i = 0; i < 4; i++)
        GL16(gB + (size_t)(i * 64) * K + k2, stB + i * 4096 + wv * 512);
    }
    BARRIER();
    __builtin_amdgcn_s_setprio(1);
#pragma unroll
    for (int m = 0; m < 4; m++)
#pragma unroll
      for (int n = 0; n < 2; n++)
#pragma unroll
        for (int ks = 0; ks < 2; ks++)
          acc[m + 4][n] = __builtin_amdgcn_mfma_f32_16x16x32_bf16(af[m][ks], bf[n][ks], acc[m + 4][n], 0, 0, 0);
    __builtin_amdgcn_s_setprio(0);
    BARRIER();   // A of this buffer dead after this

    // ---- P4: stage tile t+2 A; Q4 (regs only); counted vmcnt; barrier ----
    if (st) {
#pragma unroll
      for (int i = 0; i < 4; i++)
        GL16(gA + (size_t)(i * 64) * K + k2, stA + i * 4096 + wv * 512);
    }
    __builtin_amdgcn_s_setprio(1);
#pragma unroll
    for (int m = 0; m < 4; m++)
#pragma unroll
      for (int n = 0; n < 2; n++)
#pragma unroll
        for (int ks = 0; ks < 2; ks++)
          acc[m + 4][n + 2] = __builtin_amdgcn_mfma_f32_16x16x32_bf16(af[m][ks], bf[n + 2][ks], acc[m + 4][n + 2], 0, 0, 0);
    __builtin_amdgcn_s_setprio(0);
    // tile t+1 fully landed iff only tile t+2's 8 loads remain in flight.
    if (st) asm volatile("s_waitcnt vmcnt(8)" ::: "memory");
    else    asm volatile("s_waitcnt vmcnt(0)" ::: "memory");
    BARRIER();
  }

  // ---- epilogue ----
  float bv[4];
#pragma unroll
  for (int j = 0; j < 4; j++) bv[j] = bias[n0 + wn + j * 16 + lc];
#pragma unroll
  for (int i = 0; i < 8; i++) {
#pragma unroll
    for (int j = 0; j < 4; j++) {
#pragma unroll
      for (int r = 0; r < 4; r++) {
        size_t idx = (size_t)(m0 + wm + i * 16 + quad * 4 + r) * N + (n0 + wn + j * 16 + lc);
        float v = acc[i][j][r] + bv[j];
        if (OUT_F32) ((float*)Cout)[idx] = v;
        else         ((unsigned short*)Cout)[idx] = f2bf(v);
      }
    }
  }
}

// ---- flash attention, paired q-tiles (j, 31-j), XCD-grouped blocks ----
#define LP_STRIDE 68   // pad: pf b128 reads land 2-way/bank (free)
__global__ __launch_bounds__(256, 4)
void k_flash(const unsigned short* __restrict__ qkv,
             const unsigned short* __restrict__ vt,
             unsigned short* __restrict__ y) {
  __shared__ unsigned short lK[64 * 64];
  __shared__ unsigned short lVT[64 * 64];
  __shared__ unsigned short lP[4][2][16 * LP_STRIDE];
  int tid = threadIdx.x, lane = tid & 63, wv = tid >> 6;
  int lc = lane & 15, quad = lane >> 4;
  int sw = lc & 7;

  // XCD grouping: dispatch heuristic XCD = raw%8.  Map so each XCD owns
  // 8 bh values with ALL 16 q-pair blocks of each -> K/V stay in that
  // XCD's L2 (8 x 512 KB = 4 MB).  Bijective: raw=(c<<3)|xcd, c=(j<<3)|(bh&7).
  int raw = blockIdx.y * 16 + blockIdx.x;  // 0..1023
  int bh  = (raw & 7) * 8 + ((raw >> 3) & 7);  // 0..63
  int j   = raw >> 6;                          // 0..15
  int b = bh >> 4, h = bh & 15;
  int qtA = j, qtB = 31 - j;
  int qrA = qtA * 64 + wv * 16;
  int qrB = qtB * 64 + wv * 16;

  short8 qfA[2], qfB[2];
  {
    const unsigned short* qp = qkv + (size_t)(b * 2048 + qrA + lc) * 3072 + h * 64 + quad * 8;
    qfA[0] = *(const short8*)qp;
    qfA[1] = *(const short8*)(qp + 32);
  }
  {
    const unsigned short* qp = qkv + (size_t)(b * 2048 + qrB + lc) * 3072 + h * 64 + quad * 8;
    qfB[0] = *(const short8*)qp;
    qfB[1] = *(const short8*)(qp + 32);
  }

  float rsA[4] = {0.f, 0.f, 0.f, 0.f}, rsB[4] = {0.f, 0.f, 0.f, 0.f};
  floatx4 oA[4], oB[4];
#pragma unroll
  for (int dt = 0; dt < 4; dt++) {
    oA[dt] = (floatx4){0.f, 0.f, 0.f, 0.f};
    oB[dt] = (floatx4){0.f, 0.f, 0.f, 0.f};
  }

  int srow = tid >> 3;
  int scol = ((tid & 7) ^ (srow & 7)) * 8;    // swizzled gather column
  const unsigned short* gK = qkv + (size_t)(b * 2048 + srow) * 3072 + 1024 + h * 64 + scol;
  const unsigned short* gV = vt + (size_t)(bh * 64 + srow) * 2048 + scol;

  const float SC2 = 0.18033688011f;   // (1/sqrt(64)) * log2(e)
  int nt = qtB + 1;

  for (int kv = 0; kv < nt; kv++) {
    int kv0 = kv * 64;
#pragma unroll
    for (int c = 0; c < 2; c++) {
      GL16(gK + (size_t)(kv0 + 32 * c) * 3072, lK + (32 * c + 8 * wv) * 64);
      GL16(gV + (size_t)(32 * c) * 2048 + kv0, lVT + (32 * c + 8 * wv) * 64);
    }
    __syncthreads();

    bool withA = (kv <= qtA);

    // ---- S = Q K^T for both q-tiles, sharing K fragments ----
    floatx4 sB[4], sA[4];
    __builtin_amdgcn_s_setprio(1);
#pragma unroll
    for (int n = 0; n < 4; n++) {
      short8 kf0 = *(const short8*)(lK + (n * 16 + lc) * 64 + ((quad ^ sw) * 8));
      short8 kf1 = *(const short8*)(lK + (n * 16 + lc) * 64 + (((4 + quad) ^ sw) * 8));
      floatx4 t = (floatx4){0.f, 0.f, 0.f, 0.f};
      t = __builtin_amdgcn_mfma_f32_16x16x32_bf16(qfB[0], kf0, t, 0, 0, 0);
      t = __builtin_amdgcn_mfma_f32_16x16x32_bf16(qfB[1], kf1, t, 0, 0, 0);
      sB[n] = t;
      if (withA) {
        floatx4 u = (floatx4){0.f, 0.f, 0.f, 0.f};
        u = __builtin_amdgcn_mfma_f32_16x16x32_bf16(qfA[0], kf0, u, 0, 0, 0);
        u = __builtin_amdgcn_mfma_f32_16x16x32_bf16(qfA[1], kf1, u, 0, 0, 0);
        sA[n] = u;
      }
    }
    __builtin_amdgcn_s_setprio(0);

    // ---- softmax numerators (no max subtraction), P -> LDS (trunc pack) ----
    {
      bool diag = (kv == qtB);
#pragma unroll
      for (int n = 0; n < 4; n++)
#pragma unroll
        for (int r = 0; r < 4; r++) {
          float arg = sB[n][r] * SC2;
          if (diag && (kv0 + n * 16 + lc > qrB + quad * 4 + r)) arg = -__builtin_inff();
          float p = __builtin_amdgcn_exp2f(arg);
          rsB[r] += p;
          lP[wv][0][(quad * 4 + r) * LP_STRIDE + n * 16 + lc] = f2bf_trunc(p);
        }
    }
    if (withA) {
      bool diag = (kv == qtA);
#pragma unroll
      for (int n = 0; n < 4; n++)
#pragma unroll
        for (int r = 0; r < 4; r++) {
          float arg = sA[n][r] * SC2;
          if (diag && (kv0 + n * 16 + lc > qrA + quad * 4 + r)) arg = -__builtin_inff();
          float p = __builtin_amdgcn_exp2f(arg);
          rsA[r] += p;
          lP[wv][1][(quad * 4 + r) * LP_STRIDE + n * 16 + lc] = f2bf_trunc(p);
        }
    }

    // ---- O += P @ V, sharing V fragments (same-wave lgkmcnt orders lP) ----
    __builtin_amdgcn_s_setprio(1);
#pragma unroll
    for (int s2 = 0; s2 < 2; s2++) {
      short8 pfB = *(const short8*)(&lP[wv][0][0] + lc * LP_STRIDE + s2 * 32 + quad * 8);
      short8 pfA;
      if (withA) pfA = *(const short8*)(&lP[wv][1][0] + lc * LP_STRIDE + s2 * 32 + quad * 8);
#pragma unroll
      for (int dt = 0; dt < 4; dt++) {
        short8 vf = *(const short8*)(lVT + (dt * 16 + lc) * 64 + (((s2 * 4 + quad) ^ sw) * 8));
        oB[dt] = __builtin_amdgcn_mfma_f32_16x16x32_bf16(pfB, vf, oB[dt], 0, 0, 0);
        if (withA) oA[dt] = __builtin_amdgcn_mfma_f32_16x16x32_bf16(pfA, vf, oA[dt], 0, 0, 0);
      }
    }
    __builtin_amdgcn_s_setprio(0);
    __syncthreads();   // protect lK/lVT before next stage
  }

  // ---- epilogue: one row-sum butterfly, normalize, store both tiles ----
#pragma unroll
  for (int off = 1; off < 16; off <<= 1)
#pragma unroll
    for (int r = 0; r < 4; r++) {
      rsA[r] += __shfl_xor(rsA[r], off);
      rsB[r] += __shfl_xor(rsB[r], off);
    }
#pragma unroll
  for (int r = 0; r < 4; r++) {
    float invA = 1.0f / rsA[r];
    float invB = 1.0f / rsB[r];
#pragma unroll
    for (int dt = 0; dt < 4; dt++) {
      size_t ia = (size_t)(b * 2048 + qrA + quad * 4 + r) * 1024 + h * 64 + dt * 16 + lc;
      size_t ib = (size_t)(b * 2048 + qrB + quad * 4 + r) * 1024 + h * 64 + dt * 16 + lc;
      y[ia] = f2bf(oA[dt][r] * invA);
      y[ib] = f2bf(oB[dt][r] * invB);
    }
  }
}

extern "C" void kernel_launch(void* const* d_in, const int* in_sizes, int n_in,
                              void* d_out, int out_size, void* d_ws, size_t ws_size,
                              hipStream_t stream) {
  const float* x      = (const float*)d_in[0];
  const float* W_attn = (const float*)d_in[1];
  const float* b_attn = (const float*)d_in[2];
  const float* W_proj = (const float*)d_in[3];
  const float* b_proj = (const float*)d_in[4];

  char* ws = (char*)d_ws;
  unsigned short* xb     = (unsigned short*)ws;                    // 16.8 MB (reused as y)
  unsigned short* wattnT = (unsigned short*)(ws + 16777216);       // 6.3 MB
  unsigned short* wprojT = (unsigned short*)(ws + 23068672);       // 2.1 MB
  unsigned short* qkv    = (unsigned short*)(ws + 25165824);       // 50.3 MB
  unsigned short* vt     = (unsigned short*)(ws + 75497472);       // 16.8 MB -> total 92.3 MB
  unsigned short* y      = xb;   // xb dead after QKV GEMM

  k_cvt<<<8192, 256, 0, stream>>>(x, xb, 8388608 / 4);
  k_tw<<<dim3(96, 32), dim3(32, 8), 0, stream>>>(W_attn, wattnT, 1024, 3072);
  k_tw<<<dim3(32, 32), dim3(32, 8), 0, stream>>>(W_proj, wprojT, 1024, 1024);
  // QKV GEMM: grid 12x32 = 384 blocks (256x256 tiles)
  k_gemm8<0><<<dim3(12, 32), 512, 0, stream>>>(xb, wattnT, b_attn, qkv, 8192, 3072, 1024);
  k_tv<<<dim3(64, 2, 64), dim3(32, 8), 0, stream>>>(qkv, vt);
  k_flash<<<dim3(16, 64), 256, 0, stream>>>(qkv, vt, y);
  // proj GEMM: grid 4x32 = 128 blocks
  k_gemm8<1><<<dim3(4, 32), 512, 0, stream>>>(y, wprojT, b_proj, d_out, 8192, 1024, 1024);
}

// Round 6
// 252.962 us; speedup vs baseline: 1.2326x; 1.0490x over previous
//
#include <hip/hip_runtime.h>
#include <stdint.h>

// ---------------------------------------------------------------------------
// CausalSelfAttention: x[4,2048,1024] -> qkv -> flash attn -> proj
// Round 9: GEMM grids made exact round multiples of 256 CUs (tail removal):
//   QKV: NF=3 -> 256x192 tiles, 16x32 = 512 blocks = 2 exact rounds
//   proj: NF=2 -> 256x128 tiles,  8x32 = 256 blocks = 1 exact round
// (was 384 = 1.5 rounds / 128 = 0.5 rounds; occupancy counter showed 15%).
// K-loop: 2 MFMA phases (m0-3, m4-7; 8*NF MFMA each) + staging phase with
// derived waits: stage-B(t+2) in P2 (B dead after P1-end barrier), stage-A
// (t+2) in P3 (A dead after P2-end barrier), ONE counted vmcnt(4+NF)/tile.
// Flash (XCD-grouped, R8 version) unchanged.  T1/T2 swizzles kept.
// ---------------------------------------------------------------------------

typedef __attribute__((ext_vector_type(8))) short short8;   // 8 bf16 (4 VGPRs)
typedef __attribute__((ext_vector_type(4))) float floatx4;  // MFMA C/D frag

#define AS1C(p) ((const __attribute__((address_space(1))) void*)(p))
#define AS3(p)  ((__attribute__((address_space(3))) void*)(p))
#define GL16(src, dst) __builtin_amdgcn_global_load_lds(AS1C(src), AS3(dst), 16, 0, 0)
#define BARRIER() do { asm volatile("" ::: "memory"); __builtin_amdgcn_s_barrier(); asm volatile("" ::: "memory"); } while (0)

__device__ __forceinline__ unsigned short f2bf(float f) {
  unsigned int u = __builtin_bit_cast(unsigned int, f);
  u = (u + 0x7fffu + ((u >> 16) & 1u)) >> 16;   // RNE
  return (unsigned short)u;
}
__device__ __forceinline__ unsigned short f2bf_trunc(float f) {
  return (unsigned short)(__builtin_bit_cast(unsigned int, f) >> 16);
}

// ---- fp32 -> bf16 elementwise (x4 vectorized) ----
__global__ void k_cvt(const float* __restrict__ in, unsigned short* __restrict__ out, int n4) {
  int i = blockIdx.x * blockDim.x + threadIdx.x;
  if (i < n4) {
    float4 v = ((const float4*)in)[i];
    ushort4 o;
    o.x = f2bf(v.x); o.y = f2bf(v.y); o.z = f2bf(v.z); o.w = f2bf(v.w);
    ((ushort4*)out)[i] = o;
  }
}

// ---- transpose fp32 [K][N] -> bf16 [N][K] (weights) ----
__global__ void k_tw(const float* __restrict__ in, unsigned short* __restrict__ out, int K, int N) {
  __shared__ float t[32][33];
  int n0 = blockIdx.x * 32, k0 = blockIdx.y * 32;
  int tx = threadIdx.x, ty = threadIdx.y;
#pragma unroll
  for (int i = 0; i < 4; i++)
    t[ty + 8 * i][tx] = in[(size_t)(k0 + ty + 8 * i) * N + n0 + tx];
  __syncthreads();
#pragma unroll
  for (int i = 0; i < 4; i++)
    out[(size_t)(n0 + ty + 8 * i) * K + k0 + tx] = f2bf(t[tx][ty + 8 * i]);
}

// ---- transpose V slice of qkv (bf16) -> VT[bh][d][t] ----
__global__ void k_tv(const unsigned short* __restrict__ qkv, unsigned short* __restrict__ vt) {
  __shared__ unsigned short t[32][33];
  int t0 = blockIdx.x * 32;         // time tile
  int d0 = blockIdx.y * 32;         // head-dim tile (0 or 32)
  int bh = blockIdx.z;              // 0..63
  int b = bh >> 4, h = bh & 15;
  int tx = threadIdx.x, ty = threadIdx.y;
#pragma unroll
  for (int i = 0; i < 4; i++)
    t[ty + 8 * i][tx] = qkv[(size_t)(b * 2048 + t0 + ty + 8 * i) * 3072 + 2048 + h * 64 + d0 + tx];
  __syncthreads();
#pragma unroll
  for (int i = 0; i < 4; i++)
    vt[(size_t)(bh * 64 + d0 + ty + 8 * i) * 2048 + t0 + tx] = t[tx][ty + 8 * i];
}

// ---------------------------------------------------------------------------
// 256x(NF*64)-tile bf16 GEMM, C = A[M,K] @ Bt[N,K]^T + bias.
// 8 waves: wm=(wv>>2)*128, wn=(wv&3)*NF*16 -> per-wave 128x(NF*16), acc[8][NF].
// Per K-tile: P1 {read af m0-3 + bf all | BAR | 8*NF MFMA | BAR},
//             P2 {read af m4-7, stage B(t+2) | BAR | 8*NF MFMA | BAR},
//             P3 {stage A(t+2), vmcnt(4+NF), BAR}.
// Safety: B-LDS dead after P1-end barrier (bf consumed pre-barrier via MFMA
// lgkm waits); A-LDS dead after P2-end barrier; staging targets parity t&1
// which tile t+1 does NOT read; vmcnt(4+NF)+barrier proves t+1 landed.
// ---------------------------------------------------------------------------
template <int OUT_F32, int NF>
__global__ __launch_bounds__(512, 2)
void k_gemm8(const unsigned short* __restrict__ A,
             const unsigned short* __restrict__ Bt,
             const float* __restrict__ bias,
             void* __restrict__ Cout, int M, int N, int K) {
  __shared__ unsigned short lA[2][256 * 64];        // 64 KiB
  __shared__ unsigned short lB[2][NF * 64 * 64];    // 48 (NF=3) / 32 (NF=2) KiB
  int tid = threadIdx.x;
  int lane = tid & 63, wv = tid >> 6;               // 8 waves
  int lc = lane & 15, quad = lane >> 4;
  int sw = lc & 7;

  // T1: XCD-aware block swizzle (nwg % 8 == 0 for both launches)
  unsigned nbx = gridDim.x;
  unsigned nwg = nbx * gridDim.y;
  unsigned flat = blockIdx.y * nbx + blockIdx.x;
  unsigned cpx = nwg >> 3;
  unsigned tile = (flat & 7u) * cpx + (flat >> 3);
  int n0 = (int)(tile % nbx) * (NF * 64);
  int m0 = (int)(tile / nbx) * 256;

  int wm = (wv >> 2) * 128;         // 0,128
  int wn = (wv & 3) * (NF * 16);    // 4 N-waves

  floatx4 acc[8][NF];
#pragma unroll
  for (int i = 0; i < 8; i++)
#pragma unroll
    for (int j = 0; j < NF; j++) acc[i][j] = (floatx4){0.f, 0.f, 0.f, 0.f};

  // staging geometry: one gload issue = 512 thr x 16B = 8 KiB = 64 rows
  int srow = tid >> 3;                          // 0..63
  int scol = ((tid & 7) ^ (srow & 7)) * 8;      // inverse-swizzled source chunk
  const unsigned short* gA = A + (size_t)(m0 + srow) * K + scol;
  const unsigned short* gB = Bt + (size_t)(n0 + srow) * K + scol;

  int NT = K >> 6;

  // prologue: stage K-tiles 0 (buf0) and 1 (buf1); wait tile 0 landed.
#pragma unroll
  for (int i = 0; i < 4; i++)  GL16(gA + (size_t)(i * 64) * K, &lA[0][i * 4096 + wv * 512]);
#pragma unroll
  for (int i = 0; i < NF; i++) GL16(gB + (size_t)(i * 64) * K, &lB[0][i * 4096 + wv * 512]);
#pragma unroll
  for (int i = 0; i < 4; i++)  GL16(gA + (size_t)(i * 64) * K + 64, &lA[1][i * 4096 + wv * 512]);
#pragma unroll
  for (int i = 0; i < NF; i++) GL16(gB + (size_t)(i * 64) * K + 64, &lB[1][i * 4096 + wv * 512]);
  if constexpr (NF == 3) asm volatile("s_waitcnt vmcnt(7)" ::: "memory");
  else                   asm volatile("s_waitcnt vmcnt(6)" ::: "memory");
  __builtin_amdgcn_s_barrier();
  asm volatile("" ::: "memory");

  for (int t = 0; t < NT; ++t) {
    const unsigned short* bufA = lA[t & 1];
    const unsigned short* bufB = lB[t & 1];
    unsigned short* stA = lA[t & 1];            // tile t+2 lands in same parity
    unsigned short* stB = lB[t & 1];
    int k2 = (t + 2) << 6;
    bool st = (t + 2) < NT;

    short8 af[4][2], bf[NF][2];

    // ---- P1: read af m0-3 (8) + bf all (2*NF); MFMA m0-3 x all ----
#pragma unroll
    for (int m = 0; m < 4; m++)
#pragma unroll
      for (int ks = 0; ks < 2; ks++)
        af[m][ks] = *(const short8*)(bufA + (wm + m * 16 + lc) * 64 + (((ks * 4 + quad) ^ sw) * 8));
#pragma unroll
    for (int n = 0; n < NF; n++)
#pragma unroll
      for (int ks = 0; ks < 2; ks++)
        bf[n][ks] = *(const short8*)(bufB + (wn + n * 16 + lc) * 64 + (((ks * 4 + quad) ^ sw) * 8));
    BARRIER();
    __builtin_amdgcn_s_setprio(1);
#pragma unroll
    for (int m = 0; m < 4; m++)
#pragma unroll
      for (int n = 0; n < NF; n++)
#pragma unroll
        for (int ks = 0; ks < 2; ks++)
          acc[m][n] = __builtin_amdgcn_mfma_f32_16x16x32_bf16(af[m][ks], bf[n][ks], acc[m][n], 0, 0, 0);
    __builtin_amdgcn_s_setprio(0);
    BARRIER();   // B-LDS of this parity now dead (bf held in regs)

    // ---- P2: read af m4-7 (reuse regs); stage B(t+2); MFMA m4-7 x all ----
#pragma unroll
    for (int m = 0; m < 4; m++)
#pragma unroll
      for (int ks = 0; ks < 2; ks++)
        af[m][ks] = *(const short8*)(bufA + (wm + (m + 4) * 16 + lc) * 64 + (((ks * 4 + quad) ^ sw) * 8));
    if (st) {
#pragma unroll
      for (int i = 0; i < NF; i++)
        GL16(gB + (size_t)(i * 64) * K + k2, stB + i * 4096 + wv * 512);
    }
    BARRIER();
    __builtin_amdgcn_s_setprio(1);
#pragma unroll
    for (int m = 0; m < 4; m++)
#pragma unroll
      for (int n = 0; n < NF; n++)
#pragma unroll
        for (int ks = 0; ks < 2; ks++)
          acc[m + 4][n] = __builtin_amdgcn_mfma_f32_16x16x32_bf16(af[m][ks], bf[n][ks], acc[m + 4][n], 0, 0, 0);
    __builtin_amdgcn_s_setprio(0);
    BARRIER();   // A-LDS of this parity now dead

    // ---- P3: stage A(t+2); counted vmcnt; barrier ----
    if (st) {
#pragma unroll
      for (int i = 0; i < 4; i++)
        GL16(gA + (size_t)(i * 64) * K + k2, stA + i * 4096 + wv * 512);
      // outstanding = t+2's (4+NF) loads exactly => t+1's proven landed.
      if constexpr (NF == 3) asm volatile("s_waitcnt vmcnt(7)" ::: "memory");
      else                   asm volatile("s_waitcnt vmcnt(6)" ::: "memory");
    } else {
      asm volatile("s_waitcnt vmcnt(0)" ::: "memory");
    }
    BARRIER();   // every wave waited its own vmcnt => t+1 fully visible
  }

  // ---- epilogue ----
  float bv[NF];
#pragma unroll
  for (int j = 0; j < NF; j++) bv[j] = bias[n0 + wn + j * 16 + lc];
#pragma unroll
  for (int i = 0; i < 8; i++) {
#pragma unroll
    for (int j = 0; j < NF; j++) {
#pragma unroll
      for (int r = 0; r < 4; r++) {
        size_t idx = (size_t)(m0 + wm + i * 16 + quad * 4 + r) * N + (n0 + wn + j * 16 + lc);
        float v = acc[i][j][r] + bv[j];
        if (OUT_F32) ((float*)Cout)[idx] = v;
        else         ((unsigned short*)Cout)[idx] = f2bf(v);
      }
    }
  }
}

// ---- flash attention, paired q-tiles (j, 31-j), XCD-grouped blocks ----
#define LP_STRIDE 68   // pad: pf b128 reads land 2-way/bank (free)
__global__ __launch_bounds__(256, 4)
void k_flash(const unsigned short* __restrict__ qkv,
             const unsigned short* __restrict__ vt,
             unsigned short* __restrict__ y) {
  __shared__ unsigned short lK[64 * 64];
  __shared__ unsigned short lVT[64 * 64];
  __shared__ unsigned short lP[4][2][16 * LP_STRIDE];
  int tid = threadIdx.x, lane = tid & 63, wv = tid >> 6;
  int lc = lane & 15, quad = lane >> 4;
  int sw = lc & 7;

  // XCD grouping: dispatch heuristic XCD = raw%8.  Each XCD owns 8 bh values
  // with ALL 16 q-pair blocks of each -> K/V stay in that XCD's L2 (4 MB).
  int raw = blockIdx.y * 16 + blockIdx.x;      // 0..1023
  int bh  = (raw & 7) * 8 + ((raw >> 3) & 7);  // 0..63
  int j   = raw >> 6;                          // 0..15
  int b = bh >> 4, h = bh & 15;
  int qtA = j, qtB = 31 - j;
  int qrA = qtA * 64 + wv * 16;
  int qrB = qtB * 64 + wv * 16;

  short8 qfA[2], qfB[2];
  {
    const unsigned short* qp = qkv + (size_t)(b * 2048 + qrA + lc) * 3072 + h * 64 + quad * 8;
    qfA[0] = *(const short8*)qp;
    qfA[1] = *(const short8*)(qp + 32);
  }
  {
    const unsigned short* qp = qkv + (size_t)(b * 2048 + qrB + lc) * 3072 + h * 64 + quad * 8;
    qfB[0] = *(const short8*)qp;
    qfB[1] = *(const short8*)(qp + 32);
  }

  float rsA[4] = {0.f, 0.f, 0.f, 0.f}, rsB[4] = {0.f, 0.f, 0.f, 0.f};
  floatx4 oA[4], oB[4];
#pragma unroll
  for (int dt = 0; dt < 4; dt++) {
    oA[dt] = (floatx4){0.f, 0.f, 0.f, 0.f};
    oB[dt] = (floatx4){0.f, 0.f, 0.f, 0.f};
  }

  int srow = tid >> 3;
  int scol = ((tid & 7) ^ (srow & 7)) * 8;    // swizzled gather column
  const unsigned short* gK = qkv + (size_t)(b * 2048 + srow) * 3072 + 1024 + h * 64 + scol;
  const unsigned short* gV = vt + (size_t)(bh * 64 + srow) * 2048 + scol;

  const float SC2 = 0.18033688011f;   // (1/sqrt(64)) * log2(e)
  int nt = qtB + 1;

  for (int kv = 0; kv < nt; kv++) {
    int kv0 = kv * 64;
#pragma unroll
    for (int c = 0; c < 2; c++) {
      GL16(gK + (size_t)(kv0 + 32 * c) * 3072, lK + (32 * c + 8 * wv) * 64);
      GL16(gV + (size_t)(32 * c) * 2048 + kv0, lVT + (32 * c + 8 * wv) * 64);
    }
    __syncthreads();

    bool withA = (kv <= qtA);

    // ---- S = Q K^T for both q-tiles, sharing K fragments ----
    floatx4 sB[4], sA[4];
    __builtin_amdgcn_s_setprio(1);
#pragma unroll
    for (int n = 0; n < 4; n++) {
      short8 kf0 = *(const short8*)(lK + (n * 16 + lc) * 64 + ((quad ^ sw) * 8));
      short8 kf1 = *(const short8*)(lK + (n * 16 + lc) * 64 + (((4 + quad) ^ sw) * 8));
      floatx4 t = (floatx4){0.f, 0.f, 0.f, 0.f};
      t = __builtin_amdgcn_mfma_f32_16x16x32_bf16(qfB[0], kf0, t, 0, 0, 0);
      t = __builtin_amdgcn_mfma_f32_16x16x32_bf16(qfB[1], kf1, t, 0, 0, 0);
      sB[n] = t;
      if (withA) {
        floatx4 u = (floatx4){0.f, 0.f, 0.f, 0.f};
        u = __builtin_amdgcn_mfma_f32_16x16x32_bf16(qfA[0], kf0, u, 0, 0, 0);
        u = __builtin_amdgcn_mfma_f32_16x16x32_bf16(qfA[1], kf1, u, 0, 0, 0);
        sA[n] = u;
      }
    }
    __builtin_amdgcn_s_setprio(0);

    // ---- softmax numerators (no max subtraction), P -> LDS (trunc pack) ----
    {
      bool diag = (kv == qtB);
#pragma unroll
      for (int n = 0; n < 4; n++)
#pragma unroll
        for (int r = 0; r < 4; r++) {
          float arg = sB[n][r] * SC2;
          if (diag && (kv0 + n * 16 + lc > qrB + quad * 4 + r)) arg = -__builtin_inff();
          float p = __builtin_amdgcn_exp2f(arg);
          rsB[r] += p;
          lP[wv][0][(quad * 4 + r) * LP_STRIDE + n * 16 + lc] = f2bf_trunc(p);
        }
    }
    if (withA) {
      bool diag = (kv == qtA);
#pragma unroll
      for (int n = 0; n < 4; n++)
#pragma unroll
        for (int r = 0; r < 4; r++) {
          float arg = sA[n][r] * SC2;
          if (diag && (kv0 + n * 16 + lc > qrA + quad * 4 + r)) arg = -__builtin_inff();
          float p = __builtin_amdgcn_exp2f(arg);
          rsA[r] += p;
          lP[wv][1][(quad * 4 + r) * LP_STRIDE + n * 16 + lc] = f2bf_trunc(p);
        }
    }

    // ---- O += P @ V, sharing V fragments (same-wave lgkmcnt orders lP) ----
    __builtin_amdgcn_s_setprio(1);
#pragma unroll
    for (int s2 = 0; s2 < 2; s2++) {
      short8 pfB = *(const short8*)(&lP[wv][0][0] + lc * LP_STRIDE + s2 * 32 + quad * 8);
      short8 pfA;
      if (withA) pfA = *(const short8*)(&lP[wv][1][0] + lc * LP_STRIDE + s2 * 32 + quad * 8);
#pragma unroll
      for (int dt = 0; dt < 4; dt++) {
        short8 vf = *(const short8*)(lVT + (dt * 16 + lc) * 64 + (((s2 * 4 + quad) ^ sw) * 8));
        oB[dt] = __builtin_amdgcn_mfma_f32_16x16x32_bf16(pfB, vf, oB[dt], 0, 0, 0);
        if (withA) oA[dt] = __builtin_amdgcn_mfma_f32_16x16x32_bf16(pfA, vf, oA[dt], 0, 0, 0);
      }
    }
    __builtin_amdgcn_s_setprio(0);
    __syncthreads();   // protect lK/lVT before next stage
  }

  // ---- epilogue: one row-sum butterfly, normalize, store both tiles ----
#pragma unroll
  for (int off = 1; off < 16; off <<= 1)
#pragma unroll
    for (int r = 0; r < 4; r++) {
      rsA[r] += __shfl_xor(rsA[r], off);
      rsB[r] += __shfl_xor(rsB[r], off);
    }
#pragma unroll
  for (int r = 0; r < 4; r++) {
    float invA = 1.0f / rsA[r];
    float invB = 1.0f / rsB[r];
#pragma unroll
    for (int dt = 0; dt < 4; dt++) {
      size_t ia = (size_t)(b * 2048 + qrA + quad * 4 + r) * 1024 + h * 64 + dt * 16 + lc;
      size_t ib = (size_t)(b * 2048 + qrB + quad * 4 + r) * 1024 + h * 64 + dt * 16 + lc;
      y[ia] = f2bf(oA[dt][r] * invA);
      y[ib] = f2bf(oB[dt][r] * invB);
    }
  }
}

extern "C" void kernel_launch(void* const* d_in, const int* in_sizes, int n_in,
                              void* d_out, int out_size, void* d_ws, size_t ws_size,
                              hipStream_t stream) {
  const float* x      = (const float*)d_in[0];
  const float* W_attn = (const float*)d_in[1];
  const float* b_attn = (const float*)d_in[2];
  const float* W_proj = (const float*)d_in[3];
  const float* b_proj = (const float*)d_in[4];

  char* ws = (char*)d_ws;
  unsigned short* xb     = (unsigned short*)ws;                    // 16.8 MB (reused as y)
  unsigned short* wattnT = (unsigned short*)(ws + 16777216);       // 6.3 MB
  unsigned short* wprojT = (unsigned short*)(ws + 23068672);       // 2.1 MB
  unsigned short* qkv    = (unsigned short*)(ws + 25165824);       // 50.3 MB
  unsigned short* vt     = (unsigned short*)(ws + 75497472);       // 16.8 MB -> total 92.3 MB
  unsigned short* y      = xb;   // xb dead after QKV GEMM

  k_cvt<<<8192, 256, 0, stream>>>(x, xb, 8388608 / 4);
  k_tw<<<dim3(96, 32), dim3(32, 8), 0, stream>>>(W_attn, wattnT, 1024, 3072);
  k_tw<<<dim3(32, 32), dim3(32, 8), 0, stream>>>(W_proj, wprojT, 1024, 1024);
  // QKV GEMM: 256x192 tiles, grid 16x32 = 512 blocks = 2 exact rounds
  k_gemm8<0, 3><<<dim3(16, 32), 512, 0, stream>>>(xb, wattnT, b_attn, qkv, 8192, 3072, 1024);
  k_tv<<<dim3(64, 2, 64), dim3(32, 8), 0, stream>>>(qkv, vt);
  k_flash<<<dim3(16, 64), 256, 0, stream>>>(qkv, vt, y);
  // proj GEMM: 256x128 tiles, grid 8x32 = 256 blocks = 1 exact round
  k_gemm8<1, 2><<<dim3(8, 32), 512, 0, stream>>>(y, wprojT, b_proj, d_out, 8192, 1024, 1024);
}